// Round 9
// baseline (567.924 us; speedup 1.0000x reference)
//
#include <hip/hip_runtime.h>
#include <hip/hip_bf16.h>

#define N_FLOWS 50000
#define N_LINKS 5000
#define LPATH 8
#define PLINK 80
#define DIM 16
#define ITERS 12

typedef __attribute__((ext_vector_type(4))) float f32x4;
typedef __attribute__((ext_vector_type(2))) float f32x2;

// ds_swizzle BitMode: offset = (xor<<10) | (or<<5) | and  (within 32-lane half)
#define SWZ(x, pat) __int_as_float(__builtin_amdgcn_ds_swizzle(__float_as_int(x), (pat)))

// DPP row_ror move: dst lane gets value rotated within its 16-lane row.
template <int CTRL>
__device__ __forceinline__ float dppmov_(float x) {
    return __int_as_float(__builtin_amdgcn_update_dpp(
        0, __float_as_int(x), CTRL, 0xF, 0xF, true));
}
#define ROR1 0x121
#define ROR2 0x122
#define ROR4 0x124
#define ROR8 0x128

__device__ __forceinline__ float rcp_(float x) { return __builtin_amdgcn_rcpf(x); }
__device__ __forceinline__ float sigmoid_(float x) { return rcp_(1.f + __expf(-x)); }
__device__ __forceinline__ float tanh_(float x) { return 1.f - 2.f * rcp_(1.f + __expf(2.f * x)); }
__device__ __forceinline__ float selu_(float x) {
    const float sc = 1.0507009873554805f, al = 1.6732632423543772f;
    return x > 0.f ? sc * x : sc * al * expm1f(x);
}
__device__ __forceinline__ float softplus_(float x) {
    return fmaxf(x, 0.f) + log1pf(__expf(-fabsf(x)));
}
__device__ __forceinline__ f32x2 pkfma_(f32x2 a, f32x2 b, f32x2 c) {
    return __builtin_elementwise_fma(a, b, c);
}

// ---- one-time weight repack ----------------------------------------------
// Wpk  [j][g][k]       = pgru_Wr[k*48+g*16+j]            (768)
// Wa_t [j][k]          = att_W[k*16+j]                   (256)
// lWkr [j][g][k][2]    = {lgru_Wk, lgru_Wr}[k*48+g*16+j] (1536)
// pWk_t[c][k]          = pgru_Wk[k*48+c]                 (768)
__global__ __launch_bounds__(256) void k_prep(
    const float* __restrict__ pWr, const float* __restrict__ attW,
    const float* __restrict__ lWk, const float* __restrict__ lWr,
    const float* __restrict__ pWk,
    float* __restrict__ Wpk, float* __restrict__ Wa_t,
    float* __restrict__ lWkr, float* __restrict__ pWk_t) {
    int i = blockIdx.x * 256 + threadIdx.x;
    if (i < 768) {
        int j = i / 48, r = i % 48;
        Wpk[i] = pWr[(r % 16) * 48 + (r / 16) * 16 + j];
    } else if (i < 1024) {
        int t = i - 768;
        Wa_t[t] = attW[(t % 16) * 16 + (t / 16)];
    } else if (i < 2560) {
        int t = i - 1024;
        int slot = t & 1, idx = t >> 1;
        int j = idx / 48, r = idx % 48;
        int src = (r % 16) * 48 + (r / 16) * 16 + j;
        lWkr[t] = slot == 0 ? lWk[src] : lWr[src];
    } else if (i < 3328) {
        int t = i - 2560;
        pWk_t[t] = pWk[(t % 16) * 48 + (t / 16)];
    }
}

// ---- load per link -------------------------------------------------------
__global__ __launch_bounds__(256) void k_load(const int* __restrict__ p2l,
                                              const float* __restrict__ flow_traffic,
                                              const float* __restrict__ link_capacity,
                                              float* __restrict__ load) {
    int wave = (blockIdx.x * 256 + threadIdx.x) >> 6;
    int lane = threadIdx.x & 63;
    if (wave >= N_LINKS) return;
    float s = 0.f;
    for (int p = lane; p < PLINK; p += 64) {
        int flow = p2l[(wave * PLINK + p) * 2];
        s += flow_traffic[flow];
    }
#pragma unroll
    for (int off = 32; off; off >>= 1) s += __shfl_xor(s, off, 64);
    if (lane == 0) load[wave] = s / (link_capacity[wave] * 1e9f);
}

// ---- flow embedding ------------------------------------------------------
__global__ __launch_bounds__(256) void k_flow_init(
    const float* __restrict__ flow_traffic, const float* __restrict__ flow_packets,
    const float* __restrict__ ibg, const float* __restrict__ rate,
    const float* __restrict__ p90, const float* __restrict__ pkt_size,
    const float* __restrict__ bitrate_pb, const float* __restrict__ ipg_mean,
    const float* __restrict__ ipg_var, const float* __restrict__ pkts_pb,
    const int* __restrict__ flow_length, const float* __restrict__ flow_type,
    const float* __restrict__ W1, const float* __restrict__ b1,
    const float* __restrict__ W2, const float* __restrict__ b2,
    float* __restrict__ path_state) {
    int f = blockIdx.x * 256 + threadIdx.x;
    if (f >= N_FLOWS) return;
    float feats[13];
    feats[0] = (flow_traffic[f] - 0.1f) * 2.f;
    feats[1] = (flow_packets[f] - 0.1f) * 2.f;
    feats[2] = (ibg[f] - 0.1f) * 2.f;
    feats[3] = (rate[f] - 0.1f) * 2.f;
    feats[4] = (p90[f] - 0.1f) * 2.f;
    feats[5] = (pkt_size[f] - 0.1f) * 2.f;
    feats[6] = (bitrate_pb[f] - 0.1f) * 2.f;
    feats[7] = (ipg_mean[f] - 0.1f) * 2.f;
    feats[8] = (ipg_var[f] - 0.1f) * 2.f;
    feats[9] = (pkts_pb[f] - 0.1f) * 2.f;
    feats[10] = (float)flow_length[f];
    feats[11] = flow_type[f * 2 + 0];
    feats[12] = flow_type[f * 2 + 1];
    float h1[DIM];
#pragma unroll
    for (int j = 0; j < DIM; ++j) {
        float a = b1[j];
#pragma unroll
        for (int k = 0; k < 13; ++k) a = fmaf(feats[k], W1[k * DIM + j], a);
        h1[j] = selu_(a);
    }
#pragma unroll
    for (int j = 0; j < DIM; ++j) {
        float a = b2[j];
#pragma unroll
        for (int k = 0; k < DIM; ++k) a = fmaf(h1[k], W2[k * DIM + j], a);
        path_state[f * DIM + j] = selu_(a);
    }
}

// ---- link embedding + xform precompute (padded [link][j][4] layout) ------
__global__ __launch_bounds__(256) void k_link_init(
    const float* __restrict__ link_capacity, const float* __restrict__ load,
    const float* __restrict__ max_link_load,
    const float* __restrict__ W1, const float* __restrict__ b1,
    const float* __restrict__ W2, const float* __restrict__ b2,
    const float* __restrict__ pWk, const float* __restrict__ pb,
    float* __restrict__ link_state, float* __restrict__ xform) {
    int l = blockIdx.x * 256 + threadIdx.x;
    if (l >= N_LINKS) return;
    float feats[3];
    feats[0] = (link_capacity[l] - 0.1f) * 2.f;
    feats[1] = load[l];
    feats[2] = load[l] / max_link_load[0];
    float h1[DIM];
#pragma unroll
    for (int j = 0; j < DIM; ++j) {
        float a = b1[j];
#pragma unroll
        for (int k = 0; k < 3; ++k) a = fmaf(feats[k], W1[k * DIM + j], a);
        h1[j] = selu_(a);
    }
    float h2[DIM];
#pragma unroll
    for (int j = 0; j < DIM; ++j) {
        float a = b2[j];
#pragma unroll
        for (int k = 0; k < DIM; ++k) a = fmaf(h1[k], W2[k * DIM + j], a);
        h2[j] = selu_(a);
        link_state[l * DIM + j] = h2[j];
    }
#pragma unroll
    for (int c = 0; c < 3 * DIM; ++c) {
        float a = pb[c];
#pragma unroll
        for (int k = 0; k < DIM; ++k) a = fmaf(h2[k], pWk[k * 48 + c], a);
        xform[l * 64 + (c & 15) * 4 + (c >> 4)] = a;
    }
}

// ---- flow pass: 2 flows per 16-lane group, packed-pair (A,B) math --------
// hbuf interleaved {hA,hB}: f32x4 reads yield natural (A,B) f32x2 pairs for
// v_pk_fma_f32 (weights splat via op_sel). Chains stay 16-deep per gate.
template <bool LAST>
__global__ __launch_bounds__(256) void k_flow_pass(
    const int* __restrict__ l2p, const float* __restrict__ xform,
    float* __restrict__ path_state, float* __restrict__ sv,
    const float* __restrict__ Wpk, const float* __restrict__ b,
    const float* __restrict__ Wa_t, const float* __restrict__ attB,
    const float* __restrict__ link_capacity,
    const float* __restrict__ roW1, const float* __restrict__ rob1,
    const float* __restrict__ roW2, const float* __restrict__ rob2,
    const float* __restrict__ roW3, const float* __restrict__ rob3,
    float* __restrict__ out) {
    __shared__ float hbuf[16][18][2];
    __shared__ float shist[LAST ? 32 : 1][LPATH + 1][17];
    int tid = threadIdx.x;
    int gi = tid >> 4, j = tid & 15;
    int base = blockIdx.x * 32;
    int fA = base + gi;
    int fB = base + 16 + gi;
    int fAc = fA < N_FLOWS ? fA : N_FLOWS - 1;
    int fBc = fB < N_FLOWS ? fB : N_FLOWS - 1;
    float wz[16], wr[16], wh[16], wa[16];
#pragma unroll
    for (int q = 0; q < 4; ++q) {
        f32x4 vz = ((const f32x4*)(Wpk + j * 48))[q];
        f32x4 vr = ((const f32x4*)(Wpk + j * 48 + 16))[q];
        f32x4 vh = ((const f32x4*)(Wpk + j * 48 + 32))[q];
        f32x4 va = ((const f32x4*)(Wa_t + j * 16))[q];
#pragma unroll
        for (int e = 0; e < 4; ++e) {
            wz[q * 4 + e] = vz[e];
            wr[q * 4 + e] = vr[e];
            wh[q * 4 + e] = vh[e];
            wa[q * 4 + e] = va[e];
        }
    }
    float b1z = b[48 + j], b1r = b[64 + j], b1h = b[80 + j], ab = attB[j];
    int linksA[LPATH], linksB[LPATH];
    {
        int4 a0 = ((const int4*)(l2p + fAc * LPATH))[0];
        int4 a1 = ((const int4*)(l2p + fAc * LPATH))[1];
        int4 c0 = ((const int4*)(l2p + fBc * LPATH))[0];
        int4 c1 = ((const int4*)(l2p + fBc * LPATH))[1];
        linksA[0] = a0.x; linksA[1] = a0.y; linksA[2] = a0.z; linksA[3] = a0.w;
        linksA[4] = a1.x; linksA[5] = a1.y; linksA[6] = a1.z; linksA[7] = a1.w;
        linksB[0] = c0.x; linksB[1] = c0.y; linksB[2] = c0.z; linksB[3] = c0.w;
        linksB[4] = c1.x; linksB[5] = c1.y; linksB[6] = c1.z; linksB[7] = c1.w;
    }
    const f32x4* xf = (const f32x4*)xform;
    float hA = path_state[fAc * DIM + j];
    float hB = path_state[fBc * DIM + j];
    f32x4 nxA = xf[linksA[0] * 16 + j];
    f32x4 nxB = xf[linksB[0] * 16 + j];
#pragma unroll
    for (int p = 0; p <= LPATH; ++p) {
        *(float2*)&hbuf[gi][j][0] = make_float2(hA, hB);
        f32x2 hp[16];
#pragma unroll
        for (int q = 0; q < 8; ++q) {
            f32x4 v = ((const f32x4*)&hbuf[gi][0][0])[q];
            hp[2 * q + 0] = (f32x2){v[0], v[1]};
            hp[2 * q + 1] = (f32x2){v[2], v[3]};
        }
        if constexpr (!LAST) {
            f32x2 att2 = {ab, ab};
#pragma unroll
            for (int k = 0; k < 16; ++k)
                att2 = pkfma_(hp[k], (f32x2){wa[k], wa[k]}, att2);
            f32x2 z0 = {0.f, 0.f};
            f32x2 mn = __builtin_elementwise_min(att2, z0);
            att2 = __builtin_elementwise_max(att2, z0) + mn * 0.01f;  // leaky
            float attA = att2[0], attB_ = att2[1];
            float mA = attA, mB = attB_;
            mA = fmaxf(mA, dppmov_<ROR1>(mA)); mB = fmaxf(mB, dppmov_<ROR1>(mB));
            mA = fmaxf(mA, dppmov_<ROR2>(mA)); mB = fmaxf(mB, dppmov_<ROR2>(mB));
            mA = fmaxf(mA, dppmov_<ROR4>(mA)); mB = fmaxf(mB, dppmov_<ROR4>(mB));
            mA = fmaxf(mA, dppmov_<ROR8>(mA)); mB = fmaxf(mB, dppmov_<ROR8>(mB));
            float eA = __expf(attA - mA), eB = __expf(attB_ - mB);
            float sA = eA, sB = eB;
            sA += dppmov_<ROR1>(sA); sB += dppmov_<ROR1>(sB);
            sA += dppmov_<ROR2>(sA); sB += dppmov_<ROR2>(sB);
            sA += dppmov_<ROR4>(sA); sB += dppmov_<ROR4>(sB);
            sA += dppmov_<ROR8>(sA); sB += dppmov_<ROR8>(sB);
            sv[p * (N_FLOWS * DIM) + fA * DIM + j] = eA * rcp_(sA) * hA;
            if (fB < N_FLOWS)
                sv[p * (N_FLOWS * DIM) + fB * DIM + j] = eB * rcp_(sB) * hB;
        } else {
            shist[gi][p][j] = hA;
            shist[gi + 16][p][j] = hB;
        }
        if (p < LPATH) {
            f32x4 cxA = nxA, cxB = nxB;
            if (p + 1 < LPATH) {
                nxA = xf[linksA[p + 1] * 16 + j];
                nxB = xf[linksB[p + 1] * 16 + j];
            }
            f32x2 gz2 = {b1z, b1z}, gr2 = {b1r, b1r}, gh2 = {b1h, b1h};
#pragma unroll
            for (int k = 0; k < 16; ++k) {
                gz2 = pkfma_(hp[k], (f32x2){wz[k], wz[k]}, gz2);
                gr2 = pkfma_(hp[k], (f32x2){wr[k], wr[k]}, gr2);
                gh2 = pkfma_(hp[k], (f32x2){wh[k], wh[k]}, gh2);
            }
            float zA = sigmoid_(cxA[0] + gz2[0]);
            float rA = sigmoid_(cxA[1] + gr2[0]);
            float cA = tanh_(fmaf(rA, gh2[0], cxA[2]));
            hA = zA * hA + (1.f - zA) * cA;
            float zB = sigmoid_(cxB[0] + gz2[1]);
            float rB = sigmoid_(cxB[1] + gr2[1]);
            float cB = tanh_(fmaf(rB, gh2[1], cxB[2]));
            hB = zB * hB + (1.f - zB) * cB;
        }
    }
    if constexpr (!LAST) {
        path_state[fA * DIM + j] = hA;
        if (fB < N_FLOWS) path_state[fB * DIM + j] = hB;
    } else {
        __syncthreads();
        {  // 32 flows x 8 positions = 256 threads
            int fl = tid >> 3, t = tid & 7;
            int fg = base + fl;
            const float* s = shist[fl][t + 1];
            float h1[8];
#pragma unroll
            for (int m_ = 0; m_ < 8; ++m_) {
                float a = rob1[m_];
#pragma unroll
                for (int k = 0; k < 16; ++k) a = fmaf(s[k], roW1[k * 8 + m_], a);
                h1[m_] = selu_(a);
            }
            float h2[4];
#pragma unroll
            for (int q = 0; q < 4; ++q) {
                float a = rob2[q];
#pragma unroll
                for (int m_ = 0; m_ < 8; ++m_) a = fmaf(h1[m_], roW2[m_ * 4 + q], a);
                h2[q] = selu_(a);
            }
            float o = rob3[0];
#pragma unroll
            for (int q = 0; q < 4; ++q) o = fmaf(h2[q], roW3[q], o);
            o = softplus_(o);
            int fgc = fg < N_FLOWS ? fg : N_FLOWS - 1;
            int link = l2p[fgc * LPATH + t];
            float v = o * rcp_(link_capacity[link]);
            v += SWZ(v, 0x041F);
            v += SWZ(v, 0x081F);
            v += SWZ(v, 0x101F);
            if (t == 0 && fg < N_FLOWS) out[fg] = v;
        }
    }
}

// ---- link pass: gather-sum + packed {az,gz} link GRU + fused xform -------
// 4 links per 256-block, one wave per link (16 j-lanes x 4 p-slices).
// xh_ interleaved {x,h}; lWkr interleaved {Wk,Wr}: z=sigmoid(az+gz) sums halves.
__global__ __launch_bounds__(256, 4) void k_link_pass(
    const int* __restrict__ p2l, const float* __restrict__ sv,
    float* __restrict__ link_state,
    const float* __restrict__ lWkr, const float* __restrict__ b,
    const float* __restrict__ pWk_t, const float* __restrict__ pb,
    float* __restrict__ xform) {
    __shared__ float xh_[4][16][2];
    __shared__ float hb_[4][16];
    int tid = threadIdx.x;
    int li = tid >> 6;
    int lane = tid & 63;
    int sl = lane >> 4, j = lane & 15;
    int link = blockIdx.x * 4 + li;
    float ps = 0.f;
#pragma unroll 4
    for (int i = 0; i < PLINK / 4; ++i) {
        int p = sl + 4 * i;
        int2 fp = ((const int2*)p2l)[link * PLINK + p];
        ps += sv[fp.y * (N_FLOWS * DIM) + fp.x * DIM + j];
    }
    ps += __shfl_xor(ps, 16, 64);
    ps += __shfl_xor(ps, 32, 64);
    float h = link_state[link * DIM + j];
    if (sl == 0) *(float2*)&xh_[li][j][0] = make_float2(ps, h);
    f32x2 xh[16];
#pragma unroll
    for (int q = 0; q < 8; ++q) {
        f32x4 v = ((const f32x4*)&xh_[li][0][0])[q];
        xh[2 * q + 0] = (f32x2){v[0], v[1]};
        xh[2 * q + 1] = (f32x2){v[2], v[3]};
    }
    f32x2 azgz = {b[j], b[48 + j]};
    f32x2 argr = {b[16 + j], b[64 + j]};
    f32x2 ahgh = {b[32 + j], b[80 + j]};
    const f32x2* wkr = (const f32x2*)(lWkr + j * 96);
#pragma unroll
    for (int k = 0; k < 16; ++k) {
        azgz = pkfma_(xh[k], wkr[k], azgz);
        argr = pkfma_(xh[k], wkr[16 + k], argr);
        ahgh = pkfma_(xh[k], wkr[32 + k], ahgh);
    }
    float z = sigmoid_(azgz[0] + azgz[1]);
    float r = sigmoid_(argr[0] + argr[1]);
    float hn = z * h + (1.f - z) * tanh_(fmaf(r, ahgh[1], ahgh[0]));
    if (sl == 0) hb_[li][j] = hn;
    if (sl == 0) link_state[link * DIM + j] = hn;
    float nv[16];
#pragma unroll
    for (int q = 0; q < 4; ++q) {
        f32x4 n4 = ((const f32x4*)hb_[li])[q];
#pragma unroll
        for (int e = 0; e < 4; ++e) nv[q * 4 + e] = n4[e];
    }
    int c = lane;
    if (c < 48) {
        const float* pw = pWk_t + c * 16;
        float a = pb[c];
#pragma unroll
        for (int k = 0; k < 16; ++k) a = fmaf(nv[k], pw[k], a);
        xform[link * 64 + (c & 15) * 4 + (c >> 4)] = a;
    }
}

extern "C" void kernel_launch(void* const* d_in, const int* in_sizes, int n_in,
                              void* d_out, int out_size, void* d_ws, size_t ws_size,
                              hipStream_t stream) {
    const float* flow_traffic = (const float*)d_in[0];
    const float* flow_packets = (const float*)d_in[1];
    const float* max_link_load = (const float*)d_in[2];
    const float* flow_pkts_per_burst = (const float*)d_in[3];
    const float* flow_bitrate_per_burst = (const float*)d_in[4];
    const float* flow_packet_size = (const float*)d_in[5];
    const float* flow_type = (const float*)d_in[6];
    const float* flow_ipg_mean = (const float*)d_in[7];
    const float* ibg = (const float*)d_in[8];
    const float* flow_p90 = (const float*)d_in[9];
    const float* rate = (const float*)d_in[10];
    const float* flow_ipg_var = (const float*)d_in[11];
    const float* link_capacity = (const float*)d_in[12];
    const float* fe_W1 = (const float*)d_in[13];
    const float* fe_b1 = (const float*)d_in[14];
    const float* fe_W2 = (const float*)d_in[15];
    const float* fe_b2 = (const float*)d_in[16];
    const float* le_W1 = (const float*)d_in[17];
    const float* le_b1 = (const float*)d_in[18];
    const float* le_W2 = (const float*)d_in[19];
    const float* le_b2 = (const float*)d_in[20];
    const float* att_W = (const float*)d_in[21];
    const float* att_b = (const float*)d_in[22];
    const float* pgru_Wk = (const float*)d_in[23];
    const float* pgru_Wr = (const float*)d_in[24];
    const float* pgru_b = (const float*)d_in[25];
    const float* lgru_Wk = (const float*)d_in[26];
    const float* lgru_Wr = (const float*)d_in[27];
    const float* lgru_b = (const float*)d_in[28];
    const float* ro_W1 = (const float*)d_in[29];
    const float* ro_b1 = (const float*)d_in[30];
    const float* ro_W2 = (const float*)d_in[31];
    const float* ro_b2 = (const float*)d_in[32];
    const float* ro_W3 = (const float*)d_in[33];
    const float* ro_b3 = (const float*)d_in[34];
    const int* flow_length = (const int*)d_in[35];
    const int* l2p = (const int*)d_in[36];
    const int* p2l = (const int*)d_in[37];

    float* ws = (float*)d_ws;
    float* path_state = ws;                      // 800000
    float* link_state = ws + 800000;             // 80000
    float* sv = ws + 880000;                     // 7200000  [pos][flow][16]
    float* load = ws + 8080000;                  // 5000
    float* xform = ws + 8085000;                 // 320000   [link][16][4]
    float* Wpk = ws + 8405000;                   // 768
    float* Wa_t = ws + 8405768;                  // 256
    float* lWkr = ws + 8406024;                  // 1536 (interleaved Wk/Wr)
    float* pWk_t = ws + 8407560;                 // 768
    if (ws_size < (size_t)8408328 * 4) return;

    k_prep<<<13, 256, 0, stream>>>(pgru_Wr, att_W, lgru_Wk, lgru_Wr, pgru_Wk,
                                   Wpk, Wa_t, lWkr, pWk_t);
    k_load<<<(N_LINKS * 64 + 255) / 256, 256, 0, stream>>>(p2l, flow_traffic,
                                                           link_capacity, load);
    k_flow_init<<<(N_FLOWS + 255) / 256, 256, 0, stream>>>(
        flow_traffic, flow_packets, ibg, rate, flow_p90, flow_packet_size,
        flow_bitrate_per_burst, flow_ipg_mean, flow_ipg_var, flow_pkts_per_burst,
        flow_length, flow_type, fe_W1, fe_b1, fe_W2, fe_b2, path_state);
    k_link_init<<<(N_LINKS + 255) / 256, 256, 0, stream>>>(
        link_capacity, load, max_link_load, le_W1, le_b1, le_W2, le_b2,
        pgru_Wk, pgru_b, link_state, xform);

    int fp_grid = (N_FLOWS + 31) / 32;
    for (int it = 0; it < ITERS - 1; ++it) {
        k_flow_pass<false><<<fp_grid, 256, 0, stream>>>(
            l2p, xform, path_state, sv, Wpk, pgru_b, Wa_t, att_b,
            nullptr, nullptr, nullptr, nullptr, nullptr, nullptr, nullptr,
            nullptr);
        k_link_pass<<<N_LINKS / 4, 256, 0, stream>>>(
            p2l, sv, link_state, lWkr, lgru_b, pWk_t, pgru_b, xform);
    }
    // final iteration: no sv / no link update needed; fuse readout.
    k_flow_pass<true><<<fp_grid, 256, 0, stream>>>(
        l2p, xform, path_state, sv, Wpk, pgru_b, Wa_t, att_b,
        link_capacity, ro_W1, ro_b1, ro_W2, ro_b2, ro_W3, ro_b3,
        (float*)d_out);
}

// Round 10
// 522.790 us; speedup vs baseline: 1.0863x; 1.0863x over previous
//
#include <hip/hip_runtime.h>
#include <hip/hip_bf16.h>

#define N_FLOWS 50000
#define N_LINKS 5000
#define LPATH 8
#define PLINK 80
#define DIM 16
#define ITERS 12

typedef __attribute__((ext_vector_type(4))) float f32x4;

#define L2E 1.4426950408889634f
#define NL2E (-1.4426950408889634f)
#define P2L2E 2.8853900817779268f

// ds_swizzle BitMode: offset = (xor<<10) | (or<<5) | and  (within 32-lane half)
#define SWZ(x, pat) __int_as_float(__builtin_amdgcn_ds_swizzle(__float_as_int(x), (pat)))

// DPP row_ror move: dst lane gets value rotated within its 16-lane row.
template <int CTRL>
__device__ __forceinline__ float dppmov_(float x) {
    return __int_as_float(__builtin_amdgcn_update_dpp(
        0, __float_as_int(x), CTRL, 0xF, 0xF, true));
}
#define ROR1 0x121
#define ROR2 0x122
#define ROR4 0x124
#define ROR8 0x128

__device__ __forceinline__ float rcp_(float x) { return __builtin_amdgcn_rcpf(x); }
__device__ __forceinline__ float exp2_(float x) { return __builtin_amdgcn_exp2f(x); }
// scaled-domain gates: input already multiplied by -log2e (sigmoid) / 2log2e (tanh)
__device__ __forceinline__ float sigmoid2_(float s) { return rcp_(1.f + exp2_(s)); }
__device__ __forceinline__ float tanh2_(float s) { return 1.f - 2.f * rcp_(1.f + exp2_(s)); }
__device__ __forceinline__ float sigmoid_(float x) { return rcp_(1.f + __expf(-x)); }
__device__ __forceinline__ float selu_(float x) {
    const float sc = 1.0507009873554805f, al = 1.6732632423543772f;
    return x > 0.f ? sc * x : sc * al * expm1f(x);
}
__device__ __forceinline__ float softplus_(float x) {
    return fmaxf(x, 0.f) + log1pf(__expf(-fabsf(x)));
}

// ---- one-time weight repack (transpose + exp2-domain per-gate scaling) ---
// Wpk  [j][g][k] = pgru_Wr[k*48+g*16+j] * gate_scale(g)   (768)
// Wa_t [j][k]    = att_W[k*16+j] * L2E                    (256)
// lWk_t[j][g][k] = lgru_Wk[...] * gate_scale(g)           (768)
// lWr_t[j][g][k] = lgru_Wr[...] * gate_scale(g)           (768)
// pWk_t[c][k]    = pgru_Wk[k*48+c]  (unscaled; xform store scales)  (768)
__global__ __launch_bounds__(256) void k_prep(
    const float* __restrict__ pWr, const float* __restrict__ attW,
    const float* __restrict__ lWk, const float* __restrict__ lWr,
    const float* __restrict__ pWk,
    float* __restrict__ Wpk, float* __restrict__ Wa_t,
    float* __restrict__ lWk_t, float* __restrict__ lWr_t,
    float* __restrict__ pWk_t) {
    int i = blockIdx.x * 256 + threadIdx.x;
    if (i < 768) {
        int j = i / 48, r = i % 48;
        float sc = (r / 16) == 2 ? P2L2E : NL2E;
        Wpk[i] = pWr[(r % 16) * 48 + (r / 16) * 16 + j] * sc;
    } else if (i < 1024) {
        int t = i - 768;
        Wa_t[t] = attW[(t % 16) * 16 + (t / 16)] * L2E;
    } else if (i < 1792) {
        int t = i - 1024;
        int j = t / 48, r = t % 48;
        float sc = (r / 16) == 2 ? P2L2E : NL2E;
        lWk_t[t] = lWk[(r % 16) * 48 + (r / 16) * 16 + j] * sc;
    } else if (i < 2560) {
        int t = i - 1792;
        int j = t / 48, r = t % 48;
        float sc = (r / 16) == 2 ? P2L2E : NL2E;
        lWr_t[t] = lWr[(r % 16) * 48 + (r / 16) * 16 + j] * sc;
    } else if (i < 3328) {
        int t = i - 2560;
        pWk_t[t] = pWk[(t % 16) * 48 + (t / 16)];
    }
}

// ---- load per link -------------------------------------------------------
__global__ __launch_bounds__(256) void k_load(const int* __restrict__ p2l,
                                              const float* __restrict__ flow_traffic,
                                              const float* __restrict__ link_capacity,
                                              float* __restrict__ load) {
    int wave = (blockIdx.x * 256 + threadIdx.x) >> 6;
    int lane = threadIdx.x & 63;
    if (wave >= N_LINKS) return;
    float s = 0.f;
    for (int p = lane; p < PLINK; p += 64) {
        int flow = p2l[(wave * PLINK + p) * 2];
        s += flow_traffic[flow];
    }
#pragma unroll
    for (int off = 32; off; off >>= 1) s += __shfl_xor(s, off, 64);
    if (lane == 0) load[wave] = s / (link_capacity[wave] * 1e9f);
}

// ---- flow embedding ------------------------------------------------------
__global__ __launch_bounds__(256) void k_flow_init(
    const float* __restrict__ flow_traffic, const float* __restrict__ flow_packets,
    const float* __restrict__ ibg, const float* __restrict__ rate,
    const float* __restrict__ p90, const float* __restrict__ pkt_size,
    const float* __restrict__ bitrate_pb, const float* __restrict__ ipg_mean,
    const float* __restrict__ ipg_var, const float* __restrict__ pkts_pb,
    const int* __restrict__ flow_length, const float* __restrict__ flow_type,
    const float* __restrict__ W1, const float* __restrict__ b1,
    const float* __restrict__ W2, const float* __restrict__ b2,
    float* __restrict__ path_state) {
    int f = blockIdx.x * 256 + threadIdx.x;
    if (f >= N_FLOWS) return;
    float feats[13];
    feats[0] = (flow_traffic[f] - 0.1f) * 2.f;
    feats[1] = (flow_packets[f] - 0.1f) * 2.f;
    feats[2] = (ibg[f] - 0.1f) * 2.f;
    feats[3] = (rate[f] - 0.1f) * 2.f;
    feats[4] = (p90[f] - 0.1f) * 2.f;
    feats[5] = (pkt_size[f] - 0.1f) * 2.f;
    feats[6] = (bitrate_pb[f] - 0.1f) * 2.f;
    feats[7] = (ipg_mean[f] - 0.1f) * 2.f;
    feats[8] = (ipg_var[f] - 0.1f) * 2.f;
    feats[9] = (pkts_pb[f] - 0.1f) * 2.f;
    feats[10] = (float)flow_length[f];
    feats[11] = flow_type[f * 2 + 0];
    feats[12] = flow_type[f * 2 + 1];
    float h1[DIM];
#pragma unroll
    for (int j = 0; j < DIM; ++j) {
        float a = b1[j];
#pragma unroll
        for (int k = 0; k < 13; ++k) a = fmaf(feats[k], W1[k * DIM + j], a);
        h1[j] = selu_(a);
    }
#pragma unroll
    for (int j = 0; j < DIM; ++j) {
        float a = b2[j];
#pragma unroll
        for (int k = 0; k < DIM; ++k) a = fmaf(h1[k], W2[k * DIM + j], a);
        path_state[f * DIM + j] = selu_(a);
    }
}

// ---- link embedding + xform precompute (padded [link][j][4], scaled) -----
__global__ __launch_bounds__(256) void k_link_init(
    const float* __restrict__ link_capacity, const float* __restrict__ load,
    const float* __restrict__ max_link_load,
    const float* __restrict__ W1, const float* __restrict__ b1,
    const float* __restrict__ W2, const float* __restrict__ b2,
    const float* __restrict__ pWk, const float* __restrict__ pb,
    float* __restrict__ link_state, float* __restrict__ xform) {
    int l = blockIdx.x * 256 + threadIdx.x;
    if (l >= N_LINKS) return;
    float feats[3];
    feats[0] = (link_capacity[l] - 0.1f) * 2.f;
    feats[1] = load[l];
    feats[2] = load[l] / max_link_load[0];
    float h1[DIM];
#pragma unroll
    for (int j = 0; j < DIM; ++j) {
        float a = b1[j];
#pragma unroll
        for (int k = 0; k < 3; ++k) a = fmaf(feats[k], W1[k * DIM + j], a);
        h1[j] = selu_(a);
    }
    float h2[DIM];
#pragma unroll
    for (int j = 0; j < DIM; ++j) {
        float a = b2[j];
#pragma unroll
        for (int k = 0; k < DIM; ++k) a = fmaf(h1[k], W2[k * DIM + j], a);
        h2[j] = selu_(a);
        link_state[l * DIM + j] = h2[j];
    }
#pragma unroll
    for (int c = 0; c < 3 * DIM; ++c) {
        float a = pb[c];
#pragma unroll
        for (int k = 0; k < DIM; ++k) a = fmaf(h2[k], pWk[k * 48 + c], a);
        float sc = (c < 32) ? NL2E : P2L2E;
        xform[l * 64 + (c & 15) * 4 + (c >> 4)] = a * sc;
    }
}

// ---- flow pass: 2 flows per 16-lane group (2 independent GRU chains) -----
// Scalar fmaf matvec, exp2-domain gates, DPP softmax reductions.
template <bool LAST>
__global__ __launch_bounds__(256) void k_flow_pass(
    const int* __restrict__ l2p, const float* __restrict__ xform,
    float* __restrict__ path_state, float* __restrict__ sv,
    const float* __restrict__ Wpk, const float* __restrict__ b,
    const float* __restrict__ Wa_t, const float* __restrict__ attB,
    const float* __restrict__ link_capacity,
    const float* __restrict__ roW1, const float* __restrict__ rob1,
    const float* __restrict__ roW2, const float* __restrict__ rob2,
    const float* __restrict__ roW3, const float* __restrict__ rob3,
    float* __restrict__ out) {
    __shared__ float hbuf[16][18][2];
    __shared__ float shist[LAST ? 32 : 1][LPATH + 1][17];
    int tid = threadIdx.x;
    int gi = tid >> 4, j = tid & 15;
    int base = blockIdx.x * 32;
    int fA = base + gi;
    int fB = base + 16 + gi;
    int fAc = fA < N_FLOWS ? fA : N_FLOWS - 1;
    int fBc = fB < N_FLOWS ? fB : N_FLOWS - 1;
    float wz[16], wr[16], wh[16], wa[16];
#pragma unroll
    for (int q = 0; q < 4; ++q) {
        f32x4 vz = ((const f32x4*)(Wpk + j * 48))[q];
        f32x4 vr = ((const f32x4*)(Wpk + j * 48 + 16))[q];
        f32x4 vh = ((const f32x4*)(Wpk + j * 48 + 32))[q];
        f32x4 va = ((const f32x4*)(Wa_t + j * 16))[q];
#pragma unroll
        for (int e = 0; e < 4; ++e) {
            wz[q * 4 + e] = vz[e];
            wr[q * 4 + e] = vr[e];
            wh[q * 4 + e] = vh[e];
            wa[q * 4 + e] = va[e];
        }
    }
    // biases in scaled domain: z,r * -log2e ; h * 2log2e ; att * log2e
    float b1z = NL2E * b[48 + j], b1r = NL2E * b[64 + j];
    float b1h = P2L2E * b[80 + j], ab = L2E * attB[j];
    int linksA[LPATH], linksB[LPATH];
    {
        int4 a0 = ((const int4*)(l2p + fAc * LPATH))[0];
        int4 a1 = ((const int4*)(l2p + fAc * LPATH))[1];
        int4 c0 = ((const int4*)(l2p + fBc * LPATH))[0];
        int4 c1 = ((const int4*)(l2p + fBc * LPATH))[1];
        linksA[0] = a0.x; linksA[1] = a0.y; linksA[2] = a0.z; linksA[3] = a0.w;
        linksA[4] = a1.x; linksA[5] = a1.y; linksA[6] = a1.z; linksA[7] = a1.w;
        linksB[0] = c0.x; linksB[1] = c0.y; linksB[2] = c0.z; linksB[3] = c0.w;
        linksB[4] = c1.x; linksB[5] = c1.y; linksB[6] = c1.z; linksB[7] = c1.w;
    }
    const f32x4* xf = (const f32x4*)xform;
    float hA = path_state[fAc * DIM + j];
    float hB = path_state[fBc * DIM + j];
    f32x4 nxA = xf[linksA[0] * 16 + j];
    f32x4 nxB = xf[linksB[0] * 16 + j];
#pragma unroll
    for (int p = 0; p <= LPATH; ++p) {
        *(float2*)&hbuf[gi][j][0] = make_float2(hA, hB);
        float ha[16], hb[16];
#pragma unroll
        for (int q = 0; q < 8; ++q) {
            f32x4 v = ((const f32x4*)&hbuf[gi][0][0])[q];
            ha[q * 2 + 0] = v[0];
            hb[q * 2 + 0] = v[1];
            ha[q * 2 + 1] = v[2];
            hb[q * 2 + 1] = v[3];
        }
        if constexpr (!LAST) {
            float attA = ab, attB_ = ab;
#pragma unroll
            for (int k = 0; k < 16; ++k) {
                attA = fmaf(ha[k], wa[k], attA);
                attB_ = fmaf(hb[k], wa[k], attB_);
            }
            attA = attA > 0.f ? attA : 0.01f * attA;   // leaky (homogeneous, scale-safe)
            attB_ = attB_ > 0.f ? attB_ : 0.01f * attB_;
            float mA = attA, mB = attB_;
            mA = fmaxf(mA, dppmov_<ROR1>(mA)); mB = fmaxf(mB, dppmov_<ROR1>(mB));
            mA = fmaxf(mA, dppmov_<ROR2>(mA)); mB = fmaxf(mB, dppmov_<ROR2>(mB));
            mA = fmaxf(mA, dppmov_<ROR4>(mA)); mB = fmaxf(mB, dppmov_<ROR4>(mB));
            mA = fmaxf(mA, dppmov_<ROR8>(mA)); mB = fmaxf(mB, dppmov_<ROR8>(mB));
            // att in log2 domain: exp2(diff) == exp(raw diff) -> same softmax
            float eA = exp2_(attA - mA), eB = exp2_(attB_ - mB);
            float sA = eA, sB = eB;
            sA += dppmov_<ROR1>(sA); sB += dppmov_<ROR1>(sB);
            sA += dppmov_<ROR2>(sA); sB += dppmov_<ROR2>(sB);
            sA += dppmov_<ROR4>(sA); sB += dppmov_<ROR4>(sB);
            sA += dppmov_<ROR8>(sA); sB += dppmov_<ROR8>(sB);
            sv[p * (N_FLOWS * DIM) + fA * DIM + j] = eA * rcp_(sA) * hA;
            if (fB < N_FLOWS)
                sv[p * (N_FLOWS * DIM) + fB * DIM + j] = eB * rcp_(sB) * hB;
        } else {
            shist[gi][p][j] = hA;
            shist[gi + 16][p][j] = hB;
        }
        if (p < LPATH) {
            f32x4 cxA = nxA, cxB = nxB;
            if (p + 1 < LPATH) {
                nxA = xf[linksA[p + 1] * 16 + j];
                nxB = xf[linksB[p + 1] * 16 + j];
            }
            float gzA = b1z, grA = b1r, ghA = b1h;
            float gzB = b1z, grB = b1r, ghB = b1h;
#pragma unroll
            for (int k = 0; k < 16; ++k) {
                gzA = fmaf(ha[k], wz[k], gzA);
                grA = fmaf(ha[k], wr[k], grA);
                ghA = fmaf(ha[k], wh[k], ghA);
                gzB = fmaf(hb[k], wz[k], gzB);
                grB = fmaf(hb[k], wr[k], grB);
                ghB = fmaf(hb[k], wh[k], ghB);
            }
            float zA = sigmoid2_(cxA[0] + gzA);
            float rA = sigmoid2_(cxA[1] + grA);
            float cA = tanh2_(fmaf(rA, ghA, cxA[2]));
            hA = fmaf(zA, hA - cA, cA);
            float zB = sigmoid2_(cxB[0] + gzB);
            float rB = sigmoid2_(cxB[1] + grB);
            float cB = tanh2_(fmaf(rB, ghB, cxB[2]));
            hB = fmaf(zB, hB - cB, cB);
        }
    }
    if constexpr (!LAST) {
        path_state[fA * DIM + j] = hA;
        if (fB < N_FLOWS) path_state[fB * DIM + j] = hB;
    } else {
        __syncthreads();
        {  // 32 flows x 8 positions = 256 threads
            int fl = tid >> 3, t = tid & 7;
            int fg = base + fl;
            const float* s = shist[fl][t + 1];
            float h1[8];
#pragma unroll
            for (int m_ = 0; m_ < 8; ++m_) {
                float a = rob1[m_];
#pragma unroll
                for (int k = 0; k < 16; ++k) a = fmaf(s[k], roW1[k * 8 + m_], a);
                h1[m_] = selu_(a);
            }
            float h2[4];
#pragma unroll
            for (int q = 0; q < 4; ++q) {
                float a = rob2[q];
#pragma unroll
                for (int m_ = 0; m_ < 8; ++m_) a = fmaf(h1[m_], roW2[m_ * 4 + q], a);
                h2[q] = selu_(a);
            }
            float o = rob3[0];
#pragma unroll
            for (int q = 0; q < 4; ++q) o = fmaf(h2[q], roW3[q], o);
            o = softplus_(o);
            int fgc = fg < N_FLOWS ? fg : N_FLOWS - 1;
            int link = l2p[fgc * LPATH + t];
            float v = o * rcp_(link_capacity[link]);
            v += SWZ(v, 0x041F);
            v += SWZ(v, 0x081F);
            v += SWZ(v, 0x101F);
            if (t == 0 && fg < N_FLOWS) out[fg] = v;
        }
    }
}

// ---- link pass: gather-sum of sv + link GRU (exp2 gates) + fused xform ---
// 4 links per 256-block, one wave per link (16 j-lanes x 4 p-slices).
__global__ __launch_bounds__(256, 4) void k_link_pass(
    const int* __restrict__ p2l, const float* __restrict__ sv,
    float* __restrict__ link_state,
    const float* __restrict__ lWk_t, const float* __restrict__ lWr_t,
    const float* __restrict__ b,
    const float* __restrict__ pWk_t, const float* __restrict__ pb,
    float* __restrict__ xform) {
    __shared__ float xb_[4][16];
    __shared__ float hb_[4][16];
    int tid = threadIdx.x;
    int li = tid >> 6;
    int lane = tid & 63;
    int sl = lane >> 4, j = lane & 15;
    int link = blockIdx.x * 4 + li;
    float ps = 0.f;
#pragma unroll 4
    for (int i = 0; i < PLINK / 4; ++i) {
        int p = sl + 4 * i;
        int2 fp = ((const int2*)p2l)[link * PLINK + p];
        ps += sv[fp.y * (N_FLOWS * DIM) + fp.x * DIM + j];
    }
    ps += __shfl_xor(ps, 16, 64);
    ps += __shfl_xor(ps, 32, 64);
    float h = link_state[link * DIM + j];
    if (sl == 0) { xb_[li][j] = ps; hb_[li][j] = h; }
    float xv[16], hv[16];
#pragma unroll
    for (int q = 0; q < 4; ++q) {
        f32x4 x4 = ((const f32x4*)xb_[li])[q];
        f32x4 h4 = ((const f32x4*)hb_[li])[q];
#pragma unroll
        for (int e = 0; e < 4; ++e) { xv[q * 4 + e] = x4[e]; hv[q * 4 + e] = h4[e]; }
    }
    // scaled-domain biases
    float az = NL2E * b[j], ar = NL2E * b[16 + j], ah = P2L2E * b[32 + j];
    float gz = NL2E * b[48 + j], gr = NL2E * b[64 + j], gh = P2L2E * b[80 + j];
    const float* kz = lWk_t + j * 48;
    const float* rz = lWr_t + j * 48;
#pragma unroll
    for (int k = 0; k < 16; ++k) {
        az = fmaf(xv[k], kz[k], az);
        ar = fmaf(xv[k], kz[16 + k], ar);
        ah = fmaf(xv[k], kz[32 + k], ah);
        gz = fmaf(hv[k], rz[k], gz);
        gr = fmaf(hv[k], rz[16 + k], gr);
        gh = fmaf(hv[k], rz[32 + k], gh);
    }
    float z = sigmoid2_(az + gz);
    float r = sigmoid2_(ar + gr);
    float cand = tanh2_(fmaf(r, gh, ah));
    float hn = fmaf(z, h - cand, cand);
    if (sl == 0) {
        link_state[link * DIM + j] = hn;
        hb_[li][j] = hn;  // re-broadcast new state for xform
    }
    float nv[16];
#pragma unroll
    for (int q = 0; q < 4; ++q) {
        f32x4 n4 = ((const f32x4*)hb_[li])[q];
#pragma unroll
        for (int e = 0; e < 4; ++e) nv[q * 4 + e] = n4[e];
    }
    int c = lane;
    if (c < 48) {
        const float* pw = pWk_t + c * 16;
        float a = pb[c];
#pragma unroll
        for (int k = 0; k < 16; ++k) a = fmaf(nv[k], pw[k], a);
        float sc = (c < 32) ? NL2E : P2L2E;
        xform[link * 64 + (c & 15) * 4 + (c >> 4)] = a * sc;
    }
}

extern "C" void kernel_launch(void* const* d_in, const int* in_sizes, int n_in,
                              void* d_out, int out_size, void* d_ws, size_t ws_size,
                              hipStream_t stream) {
    const float* flow_traffic = (const float*)d_in[0];
    const float* flow_packets = (const float*)d_in[1];
    const float* max_link_load = (const float*)d_in[2];
    const float* flow_pkts_per_burst = (const float*)d_in[3];
    const float* flow_bitrate_per_burst = (const float*)d_in[4];
    const float* flow_packet_size = (const float*)d_in[5];
    const float* flow_type = (const float*)d_in[6];
    const float* flow_ipg_mean = (const float*)d_in[7];
    const float* ibg = (const float*)d_in[8];
    const float* flow_p90 = (const float*)d_in[9];
    const float* rate = (const float*)d_in[10];
    const float* flow_ipg_var = (const float*)d_in[11];
    const float* link_capacity = (const float*)d_in[12];
    const float* fe_W1 = (const float*)d_in[13];
    const float* fe_b1 = (const float*)d_in[14];
    const float* fe_W2 = (const float*)d_in[15];
    const float* fe_b2 = (const float*)d_in[16];
    const float* le_W1 = (const float*)d_in[17];
    const float* le_b1 = (const float*)d_in[18];
    const float* le_W2 = (const float*)d_in[19];
    const float* le_b2 = (const float*)d_in[20];
    const float* att_W = (const float*)d_in[21];
    const float* att_b = (const float*)d_in[22];
    const float* pgru_Wk = (const float*)d_in[23];
    const float* pgru_Wr = (const float*)d_in[24];
    const float* pgru_b = (const float*)d_in[25];
    const float* lgru_Wk = (const float*)d_in[26];
    const float* lgru_Wr = (const float*)d_in[27];
    const float* lgru_b = (const float*)d_in[28];
    const float* ro_W1 = (const float*)d_in[29];
    const float* ro_b1 = (const float*)d_in[30];
    const float* ro_W2 = (const float*)d_in[31];
    const float* ro_b2 = (const float*)d_in[32];
    const float* ro_W3 = (const float*)d_in[33];
    const float* ro_b3 = (const float*)d_in[34];
    const int* flow_length = (const int*)d_in[35];
    const int* l2p = (const int*)d_in[36];
    const int* p2l = (const int*)d_in[37];

    float* ws = (float*)d_ws;
    float* path_state = ws;                      // 800000
    float* link_state = ws + 800000;             // 80000
    float* sv = ws + 880000;                     // 7200000  [pos][flow][16]
    float* load = ws + 8080000;                  // 5000
    float* xform = ws + 8085000;                 // 320000   [link][16][4]
    float* Wpk = ws + 8405000;                   // 768
    float* Wa_t = ws + 8405768;                  // 256
    float* lWk_t = ws + 8406024;                 // 768
    float* lWr_t = ws + 8406792;                 // 768
    float* pWk_t = ws + 8407560;                 // 768
    if (ws_size < (size_t)8408328 * 4) return;

    k_prep<<<13, 256, 0, stream>>>(pgru_Wr, att_W, lgru_Wk, lgru_Wr, pgru_Wk,
                                   Wpk, Wa_t, lWk_t, lWr_t, pWk_t);
    k_load<<<(N_LINKS * 64 + 255) / 256, 256, 0, stream>>>(p2l, flow_traffic,
                                                           link_capacity, load);
    k_flow_init<<<(N_FLOWS + 255) / 256, 256, 0, stream>>>(
        flow_traffic, flow_packets, ibg, rate, flow_p90, flow_packet_size,
        flow_bitrate_per_burst, flow_ipg_mean, flow_ipg_var, flow_pkts_per_burst,
        flow_length, flow_type, fe_W1, fe_b1, fe_W2, fe_b2, path_state);
    k_link_init<<<(N_LINKS + 255) / 256, 256, 0, stream>>>(
        link_capacity, load, max_link_load, le_W1, le_b1, le_W2, le_b2,
        pgru_Wk, pgru_b, link_state, xform);

    int fp_grid = (N_FLOWS + 31) / 32;
    for (int it = 0; it < ITERS - 1; ++it) {
        k_flow_pass<false><<<fp_grid, 256, 0, stream>>>(
            l2p, xform, path_state, sv, Wpk, pgru_b, Wa_t, att_b,
            nullptr, nullptr, nullptr, nullptr, nullptr, nullptr, nullptr,
            nullptr);
        k_link_pass<<<N_LINKS / 4, 256, 0, stream>>>(
            p2l, sv, link_state, lWk_t, lWr_t, lgru_b, pWk_t, pgru_b, xform);
    }
    // final iteration: no sv / no link update needed; fuse readout.
    k_flow_pass<true><<<fp_grid, 256, 0, stream>>>(
        l2p, xform, path_state, sv, Wpk, pgru_b, Wa_t, att_b,
        link_capacity, ro_W1, ro_b1, ro_W2, ro_b2, ro_W3, ro_b3,
        (float*)d_out);
}

// Round 13
// 461.436 us; speedup vs baseline: 1.2308x; 1.1330x over previous
//
#include <hip/hip_runtime.h>
#include <hip/hip_bf16.h>

#define N_FLOWS 50000
#define N_LINKS 5000
#define LPATH 8
#define PLINK 80
#define DIM 16
#define ITERS 12

typedef __attribute__((ext_vector_type(4))) float f32x4;
typedef __attribute__((ext_vector_type(8))) short bf16x8;

#define L2E 1.4426950408889634f
#define NL2E (-1.4426950408889634f)
#define P2L2E 2.8853900817779268f

// ds_swizzle BitMode: offset = (xor<<10) | (or<<5) | and  (within 32-lane half)
#define SWZ(x, pat) __int_as_float(__builtin_amdgcn_ds_swizzle(__float_as_int(x), (pat)))

// DPP row_ror move: rotate within 16-lane row (VALU pipe).
template <int CTRL>
__device__ __forceinline__ float dppmov_(float x) {
    return __int_as_float(__builtin_amdgcn_update_dpp(
        0, __float_as_int(x), CTRL, 0xF, 0xF, true));
}
#define ROR1 0x121
#define ROR2 0x122
#define ROR4 0x124
#define ROR8 0x128

__device__ __forceinline__ float rcp_(float x) { return __builtin_amdgcn_rcpf(x); }
__device__ __forceinline__ float exp2_(float x) { return __builtin_amdgcn_exp2f(x); }
__device__ __forceinline__ float sigmoid2_(float s) { return rcp_(1.f + exp2_(s)); }
__device__ __forceinline__ float tanh2_(float s) { return 1.f - 2.f * rcp_(1.f + exp2_(s)); }
__device__ __forceinline__ float selu_(float x) {
    const float sc = 1.0507009873554805f, al = 1.6732632423543772f;
    return x > 0.f ? sc * x : sc * al * expm1f(x);
}
__device__ __forceinline__ float softplus_(float x) {
    return fmaxf(x, 0.f) + log1pf(__expf(-fabsf(x)));
}
// f32 -> bf16 (RNE)
__device__ __forceinline__ ushort f2bf_(float x) {
    unsigned u = __float_as_uint(x);
    u += 0x7fffu + ((u >> 16) & 1u);
    return (ushort)(u >> 16);
}
__device__ __forceinline__ float bf2f_(ushort h) {
    return __uint_as_float(((unsigned)h) << 16);
}

// ---- one-time weight repack ----------------------------------------------
// wfrag[gate*2+isLo][lane][e] bf16: B-fragment; slot (lane,e) holds
// W[((lane>>4)*8+e)&15][lane&15] -- BOTH K-halves carry the same W rows, so
// A=[h_hi|h_lo] x B=[W|W] sums hi+lo contributions in one MFMA.
// hi frag = bf16(W*scale); lo frag = bf16(W*scale - hi).
__global__ __launch_bounds__(256) void k_prep(
    const float* __restrict__ pWr, const float* __restrict__ attW,
    const float* __restrict__ lWk, const float* __restrict__ lWr,
    const float* __restrict__ pWk,
    ushort* __restrict__ wfrag, float* __restrict__ lWk_t,
    float* __restrict__ lWr_t, float* __restrict__ pWk_t) {
    int i = blockIdx.x * 256 + threadIdx.x;
    if (i < 768) {
        int t = i;
        int j = t / 48, r = t % 48;
        float sc = (r / 16) == 2 ? P2L2E : NL2E;
        lWk_t[t] = lWk[(r % 16) * 48 + (r / 16) * 16 + j] * sc;
    } else if (i < 1536) {
        int t = i - 768;
        int j = t / 48, r = t % 48;
        float sc = (r / 16) == 2 ? P2L2E : NL2E;
        lWr_t[t] = lWr[(r % 16) * 48 + (r / 16) * 16 + j] * sc;
    } else if (i < 2304) {
        int t = i - 1536;
        pWk_t[t] = pWk[(t % 16) * 48 + (t / 16)];
    } else if (i < 6400) {
        int t = i - 2304;            // 0..4095
        int frag = t >> 9;           // 0..7 = gate*2 + isLo
        int s = t & 511;
        int lane = s >> 3;
        int e = s & 7;
        int gate = frag >> 1;
        int isLo = frag & 1;
        int n = lane & 15;
        int k = ((lane >> 4) * 8 + e) & 15;   // W rows repeat across K-halves
        float raw;
        if (gate < 3) {
            float sc = gate == 2 ? P2L2E : NL2E;
            raw = pWr[k * 48 + gate * 16 + n] * sc;
        } else {
            raw = attW[k * 16 + n] * L2E;
        }
        ushort hi = f2bf_(raw);
        wfrag[t] = isLo ? f2bf_(raw - bf2f_(hi)) : hi;
    }
}

// ---- load per link -------------------------------------------------------
__global__ __launch_bounds__(256) void k_load(const int* __restrict__ p2l,
                                              const float* __restrict__ flow_traffic,
                                              const float* __restrict__ link_capacity,
                                              float* __restrict__ load) {
    int wave = (blockIdx.x * 256 + threadIdx.x) >> 6;
    int lane = threadIdx.x & 63;
    if (wave >= N_LINKS) return;
    float s = 0.f;
    for (int p = lane; p < PLINK; p += 64) {
        int flow = p2l[(wave * PLINK + p) * 2];
        s += flow_traffic[flow];
    }
#pragma unroll
    for (int off = 32; off; off >>= 1) s += __shfl_xor(s, off, 64);
    if (lane == 0) load[wave] = s / (link_capacity[wave] * 1e9f);
}

// ---- flow embedding ------------------------------------------------------
__global__ __launch_bounds__(256) void k_flow_init(
    const float* __restrict__ flow_traffic, const float* __restrict__ flow_packets,
    const float* __restrict__ ibg, const float* __restrict__ rate,
    const float* __restrict__ p90, const float* __restrict__ pkt_size,
    const float* __restrict__ bitrate_pb, const float* __restrict__ ipg_mean,
    const float* __restrict__ ipg_var, const float* __restrict__ pkts_pb,
    const int* __restrict__ flow_length, const float* __restrict__ flow_type,
    const float* __restrict__ W1, const float* __restrict__ b1,
    const float* __restrict__ W2, const float* __restrict__ b2,
    float* __restrict__ path_state) {
    int f = blockIdx.x * 256 + threadIdx.x;
    if (f >= N_FLOWS) return;
    float feats[13];
    feats[0] = (flow_traffic[f] - 0.1f) * 2.f;
    feats[1] = (flow_packets[f] - 0.1f) * 2.f;
    feats[2] = (ibg[f] - 0.1f) * 2.f;
    feats[3] = (rate[f] - 0.1f) * 2.f;
    feats[4] = (p90[f] - 0.1f) * 2.f;
    feats[5] = (pkt_size[f] - 0.1f) * 2.f;
    feats[6] = (bitrate_pb[f] - 0.1f) * 2.f;
    feats[7] = (ipg_mean[f] - 0.1f) * 2.f;
    feats[8] = (ipg_var[f] - 0.1f) * 2.f;
    feats[9] = (pkts_pb[f] - 0.1f) * 2.f;
    feats[10] = (float)flow_length[f];
    feats[11] = flow_type[f * 2 + 0];
    feats[12] = flow_type[f * 2 + 1];
    float h1[DIM];
#pragma unroll
    for (int j = 0; j < DIM; ++j) {
        float a = b1[j];
#pragma unroll
        for (int k = 0; k < 13; ++k) a = fmaf(feats[k], W1[k * DIM + j], a);
        h1[j] = selu_(a);
    }
#pragma unroll
    for (int j = 0; j < DIM; ++j) {
        float a = b2[j];
#pragma unroll
        for (int k = 0; k < DIM; ++k) a = fmaf(h1[k], W2[k * DIM + j], a);
        path_state[f * DIM + j] = selu_(a);
    }
}

// ---- link embedding + xform precompute -----------------------------------
// xform[link][j][g] (g=0,1,2 -> z,r,h), exp2-scaled; z/r include BOTH GRU
// biases (b0+b1) folded, h includes only b0 (b1h folded into MFMA C-init).
__global__ __launch_bounds__(256) void k_link_init(
    const float* __restrict__ link_capacity, const float* __restrict__ load,
    const float* __restrict__ max_link_load,
    const float* __restrict__ W1, const float* __restrict__ b1,
    const float* __restrict__ W2, const float* __restrict__ b2,
    const float* __restrict__ pWk, const float* __restrict__ pb,
    float* __restrict__ link_state, float* __restrict__ xform) {
    int l = blockIdx.x * 256 + threadIdx.x;
    if (l >= N_LINKS) return;
    float feats[3];
    feats[0] = (link_capacity[l] - 0.1f) * 2.f;
    feats[1] = load[l];
    feats[2] = load[l] / max_link_load[0];
    float h1[DIM];
#pragma unroll
    for (int j = 0; j < DIM; ++j) {
        float a = b1[j];
#pragma unroll
        for (int k = 0; k < 3; ++k) a = fmaf(feats[k], W1[k * DIM + j], a);
        h1[j] = selu_(a);
    }
    float h2[DIM];
#pragma unroll
    for (int j = 0; j < DIM; ++j) {
        float a = b2[j];
#pragma unroll
        for (int k = 0; k < DIM; ++k) a = fmaf(h1[k], W2[k * DIM + j], a);
        h2[j] = selu_(a);
        link_state[l * DIM + j] = h2[j];
    }
#pragma unroll
    for (int c = 0; c < 3 * DIM; ++c) {
        float a = (c < 32) ? (pb[c] + pb[48 + c]) : pb[c];
#pragma unroll
        for (int k = 0; k < DIM; ++k) a = fmaf(h2[k], pWk[k * 48 + c], a);
        float sc = (c < 32) ? NL2E : P2L2E;
        xform[l * 64 + (c & 15) * 4 + (c >> 4)] = a * sc;
    }
}

// ---- flow pass: MFMA GRU (double-bf16 split), 16 flows per wave ----------
// C/D layout: col j = lane&15, row flow = (lane>>4)*4 + reg.
// A = [h_hi | h_lo] across K=32; B = [W_hi|W_hi] then [W_lo|W_lo]:
// two chained MFMAs per gate compute h@W to ~1e-5 rel (fp32-grade).
template <bool LAST>
__global__ __launch_bounds__(256) void k_flow_pass(
    const int* __restrict__ l2p, const float* __restrict__ xform,
    float* __restrict__ path_state, float* __restrict__ sv,
    const ushort* __restrict__ wfrag, const float* __restrict__ b,
    const float* __restrict__ attB) {
    __shared__ __align__(16) ushort hx[4][16][40];  // 80B rows; cols 0-15 hi, 16-31 lo
    __shared__ int lnk[4][16][8];
    int tid = threadIdx.x;
    int wid = tid >> 6, lane = tid & 63;
    int g = lane >> 4, j = lane & 15;
    int fbase = blockIdx.x * 64 + wid * 16;
    {   // stage this wave's 16x8 link table (wave-private, no barrier needed)
        int lf = lane >> 2;
        int off = (lane & 3) * 2;
        int fc = fbase + lf; if (fc >= N_FLOWS) fc = N_FLOWS - 1;
        int2 v = *(const int2*)(l2p + fc * LPATH + off);
        *(int2*)&lnk[wid][lf][off] = v;
    }
    bf16x8 WzH = *(const bf16x8*)(wfrag + (0 * 512 + lane * 8));
    bf16x8 WzL = *(const bf16x8*)(wfrag + (1 * 512 + lane * 8));
    bf16x8 WrH = *(const bf16x8*)(wfrag + (2 * 512 + lane * 8));
    bf16x8 WrL = *(const bf16x8*)(wfrag + (3 * 512 + lane * 8));
    bf16x8 WhH = *(const bf16x8*)(wfrag + (4 * 512 + lane * 8));
    bf16x8 WhL = *(const bf16x8*)(wfrag + (5 * 512 + lane * 8));
    bf16x8 WaH = *(const bf16x8*)(wfrag + (6 * 512 + lane * 8));
    bf16x8 WaL = *(const bf16x8*)(wfrag + (7 * 512 + lane * 8));
    float bh = P2L2E * b[80 + j];
    float ab = L2E * attB[j];
    f32x4 bhv = {bh, bh, bh, bh};
    f32x4 abv = {ab, ab, ab, ab};
    f32x4 zero = {0.f, 0.f, 0.f, 0.f};
    int fr[4];
    f32x4 hC;
#pragma unroll
    for (int r = 0; r < 4; ++r) {
        fr[r] = fbase + g * 4 + r;
        int fc = fr[r] < N_FLOWS ? fr[r] : N_FLOWS - 1;
        hC[r] = path_state[fc * DIM + j];
    }
#pragma unroll
    for (int p = 0; p <= LPATH; ++p) {
        bf16x8 A = {};
        if (!LAST || p < LPATH) {
            // split h -> hi+lo and transpose (C-layout -> A-frag) via LDS
#pragma unroll
            for (int r = 0; r < 4; ++r) {
                ushort hi = f2bf_(hC[r]);
                hx[wid][g * 4 + r][j] = hi;
                hx[wid][g * 4 + r][16 + j] = f2bf_(hC[r] - bf2f_(hi));
            }
            A = *(const bf16x8*)&hx[wid][j][g * 8];
        }
        if constexpr (!LAST) {
            f32x4 att = __builtin_amdgcn_mfma_f32_16x16x32_bf16(A, WaH, abv, 0, 0, 0);
            att = __builtin_amdgcn_mfma_f32_16x16x32_bf16(A, WaL, att, 0, 0, 0);
#pragma unroll
            for (int r = 0; r < 4; ++r) {
                float a = att[r];
                a = a > 0.f ? a : 0.01f * a;  // leaky (scale-safe)
                float m = a;
                m = fmaxf(m, dppmov_<ROR1>(m));
                m = fmaxf(m, dppmov_<ROR2>(m));
                m = fmaxf(m, dppmov_<ROR4>(m));
                m = fmaxf(m, dppmov_<ROR8>(m));
                float e = exp2_(a - m);
                float s = e;
                s += dppmov_<ROR1>(s);
                s += dppmov_<ROR2>(s);
                s += dppmov_<ROR4>(s);
                s += dppmov_<ROR8>(s);
                if (fr[r] < N_FLOWS)
                    sv[p * (N_FLOWS * DIM) + fr[r] * DIM + j] = e * rcp_(s) * hC[r];
            }
        } else {
            if (p > 0) {
#pragma unroll
                for (int r = 0; r < 4; ++r)
                    if (fr[r] < N_FLOWS)
                        sv[p * (N_FLOWS * DIM) + fr[r] * DIM + j] = hC[r];
            }
        }
        if (p < LPATH) {
            f32x4 Gz = __builtin_amdgcn_mfma_f32_16x16x32_bf16(A, WzH, zero, 0, 0, 0);
            Gz = __builtin_amdgcn_mfma_f32_16x16x32_bf16(A, WzL, Gz, 0, 0, 0);
            f32x4 Gr = __builtin_amdgcn_mfma_f32_16x16x32_bf16(A, WrH, zero, 0, 0, 0);
            Gr = __builtin_amdgcn_mfma_f32_16x16x32_bf16(A, WrL, Gr, 0, 0, 0);
            f32x4 Gh = __builtin_amdgcn_mfma_f32_16x16x32_bf16(A, WhH, bhv, 0, 0, 0);
            Gh = __builtin_amdgcn_mfma_f32_16x16x32_bf16(A, WhL, Gh, 0, 0, 0);
#pragma unroll
            for (int r = 0; r < 4; ++r) {
                int link = lnk[wid][g * 4 + r][p];
                f32x4 xq = *(const f32x4*)(xform + link * 64 + j * 4);
                float z = sigmoid2_(xq[0] + Gz[r]);
                float rr = sigmoid2_(xq[1] + Gr[r]);
                float cand = tanh2_(fmaf(rr, Gh[r], xq[2]));
                hC[r] = fmaf(z, hC[r] - cand, cand);
            }
        }
    }
    if constexpr (!LAST) {
#pragma unroll
        for (int r = 0; r < 4; ++r)
            if (fr[r] < N_FLOWS) path_state[fr[r] * DIM + j] = hC[r];
    }
}

// ---- link pass: gather-sum of sv + link GRU (exp2 gates) + fused xform ---
__global__ __launch_bounds__(256, 4) void k_link_pass(
    const int* __restrict__ p2l, const float* __restrict__ sv,
    float* __restrict__ link_state,
    const float* __restrict__ lWk_t, const float* __restrict__ lWr_t,
    const float* __restrict__ b,
    const float* __restrict__ pWk_t, const float* __restrict__ pb,
    float* __restrict__ xform) {
    __shared__ float xb_[4][16];
    __shared__ float hb_[4][16];
    int tid = threadIdx.x;
    int li = tid >> 6;
    int lane = tid & 63;
    int sl = lane >> 4, j = lane & 15;
    int link = blockIdx.x * 4 + li;
    float ps = 0.f;
#pragma unroll 4
    for (int i = 0; i < PLINK / 4; ++i) {
        int p = sl + 4 * i;
        int2 fp = ((const int2*)p2l)[link * PLINK + p];
        ps += sv[fp.y * (N_FLOWS * DIM) + fp.x * DIM + j];
    }
    ps += __shfl_xor(ps, 16, 64);
    ps += __shfl_xor(ps, 32, 64);
    float h = link_state[link * DIM + j];
    if (sl == 0) { xb_[li][j] = ps; hb_[li][j] = h; }
    float xv[16], hv[16];
#pragma unroll
    for (int q = 0; q < 4; ++q) {
        f32x4 x4 = ((const f32x4*)xb_[li])[q];
        f32x4 h4 = ((const f32x4*)hb_[li])[q];
#pragma unroll
        for (int e = 0; e < 4; ++e) { xv[q * 4 + e] = x4[e]; hv[q * 4 + e] = h4[e]; }
    }
    float az = NL2E * b[j], ar = NL2E * b[16 + j], ah = P2L2E * b[32 + j];
    float gz = NL2E * b[48 + j], gr = NL2E * b[64 + j], gh = P2L2E * b[80 + j];
    const float* kz = lWk_t + j * 48;
    const float* rz = lWr_t + j * 48;
#pragma unroll
    for (int k = 0; k < 16; ++k) {
        az = fmaf(xv[k], kz[k], az);
        ar = fmaf(xv[k], kz[16 + k], ar);
        ah = fmaf(xv[k], kz[32 + k], ah);
        gz = fmaf(hv[k], rz[k], gz);
        gr = fmaf(hv[k], rz[16 + k], gr);
        gh = fmaf(hv[k], rz[32 + k], gh);
    }
    float z = sigmoid2_(az + gz);
    float r = sigmoid2_(ar + gr);
    float cand = tanh2_(fmaf(r, gh, ah));
    float hn = fmaf(z, h - cand, cand);
    if (sl == 0) {
        link_state[link * DIM + j] = hn;
        hb_[li][j] = hn;
    }
    float nv[16];
#pragma unroll
    for (int q = 0; q < 4; ++q) {
        f32x4 n4 = ((const f32x4*)hb_[li])[q];
#pragma unroll
        for (int e = 0; e < 4; ++e) nv[q * 4 + e] = n4[e];
    }
    int c = lane;
    if (c < 48) {
        const float* pw = pWk_t + c * 16;
        float a = (c < 32) ? (pb[c] + pb[48 + c]) : pb[c];
#pragma unroll
        for (int k = 0; k < 16; ++k) a = fmaf(nv[k], pw[k], a);
        float sc = (c < 32) ? NL2E : P2L2E;
        xform[link * 64 + (c & 15) * 4 + (c >> 4)] = a * sc;
    }
}

// ---- readout: MLP over sv[pos 1..8] -> softplus -> /cap -> sum over L ----
__global__ __launch_bounds__(256) void k_readout(
    const float* __restrict__ sv, const int* __restrict__ l2p,
    const float* __restrict__ link_capacity,
    const float* __restrict__ W1, const float* __restrict__ b1,
    const float* __restrict__ W2, const float* __restrict__ b2,
    const float* __restrict__ W3, const float* __restrict__ b3,
    float* __restrict__ out) {
    int tid = blockIdx.x * 256 + threadIdx.x;
    int f = tid >> 3;
    int t = tid & 7;
    if (f >= N_FLOWS) return;
    const float* s = sv + (t + 1) * (N_FLOWS * DIM) + f * DIM;
    float h1[8];
#pragma unroll
    for (int m_ = 0; m_ < 8; ++m_) {
        float a = b1[m_];
#pragma unroll
        for (int k = 0; k < 16; ++k) a = fmaf(s[k], W1[k * 8 + m_], a);
        h1[m_] = selu_(a);
    }
    float h2[4];
#pragma unroll
    for (int q = 0; q < 4; ++q) {
        float a = b2[q];
#pragma unroll
        for (int m_ = 0; m_ < 8; ++m_) a = fmaf(h1[m_], W2[m_ * 4 + q], a);
        h2[q] = selu_(a);
    }
    float o = b3[0];
#pragma unroll
    for (int q = 0; q < 4; ++q) o = fmaf(h2[q], W3[q], o);
    o = softplus_(o);
    int link = l2p[f * LPATH + t];
    float v = o * rcp_(link_capacity[link]);
    v += SWZ(v, 0x041F);
    v += SWZ(v, 0x081F);
    v += SWZ(v, 0x101F);
    if (t == 0) out[f] = v;
}

extern "C" void kernel_launch(void* const* d_in, const int* in_sizes, int n_in,
                              void* d_out, int out_size, void* d_ws, size_t ws_size,
                              hipStream_t stream) {
    const float* flow_traffic = (const float*)d_in[0];
    const float* flow_packets = (const float*)d_in[1];
    const float* max_link_load = (const float*)d_in[2];
    const float* flow_pkts_per_burst = (const float*)d_in[3];
    const float* flow_bitrate_per_burst = (const float*)d_in[4];
    const float* flow_packet_size = (const float*)d_in[5];
    const float* flow_type = (const float*)d_in[6];
    const float* flow_ipg_mean = (const float*)d_in[7];
    const float* ibg = (const float*)d_in[8];
    const float* flow_p90 = (const float*)d_in[9];
    const float* rate = (const float*)d_in[10];
    const float* flow_ipg_var = (const float*)d_in[11];
    const float* link_capacity = (const float*)d_in[12];
    const float* fe_W1 = (const float*)d_in[13];
    const float* fe_b1 = (const float*)d_in[14];
    const float* fe_W2 = (const float*)d_in[15];
    const float* fe_b2 = (const float*)d_in[16];
    const float* le_W1 = (const float*)d_in[17];
    const float* le_b1 = (const float*)d_in[18];
    const float* le_W2 = (const float*)d_in[19];
    const float* le_b2 = (const float*)d_in[20];
    const float* att_W = (const float*)d_in[21];
    const float* att_b = (const float*)d_in[22];
    const float* pgru_Wk = (const float*)d_in[23];
    const float* pgru_Wr = (const float*)d_in[24];
    const float* pgru_b = (const float*)d_in[25];
    const float* lgru_Wk = (const float*)d_in[26];
    const float* lgru_Wr = (const float*)d_in[27];
    const float* lgru_b = (const float*)d_in[28];
    const float* ro_W1 = (const float*)d_in[29];
    const float* ro_b1 = (const float*)d_in[30];
    const float* ro_W2 = (const float*)d_in[31];
    const float* ro_b2 = (const float*)d_in[32];
    const float* ro_W3 = (const float*)d_in[33];
    const float* ro_b3 = (const float*)d_in[34];
    const int* flow_length = (const int*)d_in[35];
    const int* l2p = (const int*)d_in[36];
    const int* p2l = (const int*)d_in[37];

    float* ws = (float*)d_ws;
    float* path_state = ws;                      // 800000
    float* link_state = ws + 800000;             // 80000
    float* sv = ws + 880000;                     // 7200000  [pos][flow][16]
    float* load = ws + 8080000;                  // 5000
    float* xform = ws + 8085000;                 // 320000   [link][16][4]
    ushort* wfrag = (ushort*)(ws + 8405000);     // 4096 ushort (2048 float slots)
    float* lWk_t = ws + 8407048;                 // 768
    float* lWr_t = ws + 8407816;                 // 768
    float* pWk_t = ws + 8408584;                 // 768
    if (ws_size < (size_t)8409352 * 4) return;

    k_prep<<<25, 256, 0, stream>>>(pgru_Wr, att_W, lgru_Wk, lgru_Wr, pgru_Wk,
                                   wfrag, lWk_t, lWr_t, pWk_t);
    k_load<<<(N_LINKS * 64 + 255) / 256, 256, 0, stream>>>(p2l, flow_traffic,
                                                           link_capacity, load);
    k_flow_init<<<(N_FLOWS + 255) / 256, 256, 0, stream>>>(
        flow_traffic, flow_packets, ibg, rate, flow_p90, flow_packet_size,
        flow_bitrate_per_burst, flow_ipg_mean, flow_ipg_var, flow_pkts_per_burst,
        flow_length, flow_type, fe_W1, fe_b1, fe_W2, fe_b2, path_state);
    k_link_init<<<(N_LINKS + 255) / 256, 256, 0, stream>>>(
        link_capacity, load, max_link_load, le_W1, le_b1, le_W2, le_b2,
        pgru_Wk, pgru_b, link_state, xform);

    int fp_grid = (N_FLOWS + 63) / 64;  // 16 flows/wave, 4 waves/block
    for (int it = 0; it < ITERS - 1; ++it) {
        k_flow_pass<false><<<fp_grid, 256, 0, stream>>>(
            l2p, xform, path_state, sv, wfrag, pgru_b, att_b);
        k_link_pass<<<N_LINKS / 4, 256, 0, stream>>>(
            p2l, sv, link_state, lWk_t, lWr_t, lgru_b, pWk_t, pgru_b, xform);
    }
    // final iteration: write raw h history to sv; separate readout kernel.
    k_flow_pass<true><<<fp_grid, 256, 0, stream>>>(
        l2p, xform, path_state, sv, wfrag, pgru_b, att_b);
    k_readout<<<(N_FLOWS * 8 + 255) / 256, 256, 0, stream>>>(
        sv, l2p, link_capacity, ro_W1, ro_b1, ro_W2, ro_b2, ro_W3, ro_b3,
        (float*)d_out);
}